// Round 1
// baseline (5876.503 us; speedup 1.0000x reference)
//
#include <hip/hip_runtime.h>
#include <hip/hip_bf16.h>
#include <stdint.h>

#define B_    8
#define S_    1024
#define HIST_ 128
#define T_    1152
#define D_    1024
#define NH_   16
#define DH_   64
#define FF_   4096
#define L_    6
#define NROWS_ (B_*T_)   /* 9216 */

typedef __attribute__((ext_vector_type(8))) __bf16 bf16x8;
typedef __attribute__((ext_vector_type(4))) __bf16 bf16x4;
typedef __attribute__((ext_vector_type(4))) float  f32x4;

static __device__ __forceinline__ f32x4 mfma16(bf16x8 a, bf16x8 b, f32x4 c) {
  return __builtin_amdgcn_mfma_f32_16x16x32_bf16(a, b, c, 0, 0, 0);
}
static __device__ __forceinline__ void gload16(const __bf16* g, __bf16* l) {
  __builtin_amdgcn_global_load_lds((const __attribute__((address_space(1))) void*)g,
                                   (__attribute__((address_space(3))) void*)l, 16, 0, 0);
}

// ---------------- GEMM: C[M,N] = A[M,K](bf16) @ Bt[N,K]^T(bf16) + bias ----------------
// 128x128 tile, BK=32, 4 waves (2x2), each wave 64x64 via 4x4 16x16x32 MFMA frags.
template<int BF16OUT, int RELU>
__global__ __launch_bounds__(256) void gemm_k(const __bf16* __restrict__ A,
                                              const __bf16* __restrict__ Bt,
                                              const float* __restrict__ bias,
                                              void* __restrict__ Cout,
                                              int M, int N, int K) {
  __shared__ __align__(16) __bf16 As[128*32];
  __shared__ __align__(16) __bf16 Bs[128*32];
  const int tid = threadIdx.x;
  const int wv = tid >> 6, ln = tid & 63;
  const int m0 = blockIdx.y * 128, n0 = blockIdx.x * 128;
  const int wr = wv >> 1, wc = wv & 1;
  // staging: each wave covers 32 rows of A-tile and 32 rows of Bt-tile (2 loads each)
  const int srow = wv*32 + (ln>>2);
  const int scol = (ln&3)*8;
  const __bf16* ga0 = A  + (size_t)(m0 + srow)*K + scol;
  const __bf16* gb0 = Bt + (size_t)(n0 + srow)*K + scol;
  __bf16* la0 = As + (wv*32)*32;
  __bf16* lb0 = Bs + (wv*32)*32;
  const f32x4 zero = {0.f,0.f,0.f,0.f};
  f32x4 acc[4][4];
#pragma unroll
  for (int i=0;i<4;i++)
#pragma unroll
    for (int j=0;j<4;j++) acc[i][j] = zero;
  for (int kt = 0; kt < K; kt += 32) {
    gload16(ga0 + kt,                  la0);
    gload16(ga0 + kt + (size_t)16*K,   la0 + 512);
    gload16(gb0 + kt,                  lb0);
    gload16(gb0 + kt + (size_t)16*K,   lb0 + 512);
    __syncthreads();
    const __bf16* ap = As + (wr*64 + (ln&15))*32 + (ln>>4)*8;
    const __bf16* bp = Bs + (wc*64 + (ln&15))*32 + (ln>>4)*8;
    bf16x8 af[4], bf[4];
#pragma unroll
    for (int i=0;i<4;i++) { af[i] = *(const bf16x8*)(ap + i*512); bf[i] = *(const bf16x8*)(bp + i*512); }
#pragma unroll
    for (int mi=0;mi<4;mi++)
#pragma unroll
      for (int ni=0;ni<4;ni++)
        acc[mi][ni] = mfma16(af[mi], bf[ni], acc[mi][ni]);
    __syncthreads();
  }
  const int colb = n0 + wc*64 + (ln&15);
#pragma unroll
  for (int mi=0;mi<4;mi++) {
    const int row = m0 + wr*64 + mi*16 + ((ln>>4)<<2);
#pragma unroll
    for (int ni=0;ni<4;ni++) {
      const int col = colb + ni*16;
      const float bv = bias[col];
#pragma unroll
      for (int j=0;j<4;j++) {
        float v = acc[mi][ni][j] + bv;
        if (RELU) v = fmaxf(v, 0.f);
        if (BF16OUT) ((__bf16*)Cout)[(size_t)(row+j)*N + col] = (__bf16)v;
        else         ((float*)Cout)[(size_t)(row+j)*N + col] = v;
      }
    }
  }
}

// ---------------- Flash attention, causal, NH=16 DH=64, layout [B*T, NH*DH] ----------------
// one wave = 16 q rows; S^T = K*Q^T (both operands contiguous 16B loads); online softmax;
// P re-layout via per-wave LDS tile for the PV MFMA A-operand.
__global__ __launch_bounds__(256) void attn_k(const __bf16* __restrict__ Q,
                                              const __bf16* __restrict__ Km,
                                              const __bf16* __restrict__ V,
                                              __bf16* __restrict__ O) {
  __shared__ __align__(16) __bf16 Plds[4][16*40];
  const int wv = threadIdx.x >> 6, ln = threadIdx.x & 63;
  const int hd = blockIdx.y, b = blockIdx.z;
  const int q0 = blockIdx.x*64 + wv*16;
  const size_t base = (size_t)b*T_*D_ + (size_t)hd*DH_;
  const int l15 = ln & 15, g = ln >> 4;
  const int qrow = q0 + l15;
  const __bf16* qp = Q + base + (size_t)qrow*D_ + g*8;
  const bf16x8 qf0 = *(const bf16x8*)qp;
  const bf16x8 qf1 = *(const bf16x8*)(qp + 32);
  const f32x4 zero = {0.f,0.f,0.f,0.f};
  f32x4 o[4] = {zero, zero, zero, zero};
  float mrun = -3.0e38f, lrun = 0.f;
  for (int kt = 0; kt <= q0 + 15; kt += 32) {
    float p[8];
#pragma unroll
    for (int s=0;s<2;s++) {
      const __bf16* kp = Km + base + (size_t)(kt + s*16 + l15)*D_ + g*8;
      bf16x8 kf0 = *(const bf16x8*)kp;
      bf16x8 kf1 = *(const bf16x8*)(kp + 32);
      f32x4 st = zero;
      st = mfma16(kf0, qf0, st);
      st = mfma16(kf1, qf1, st);
#pragma unroll
      for (int r=0;r<4;r++) {
        const int kg = kt + s*16 + g*4 + r;
        p[s*4+r] = (kg <= qrow) ? st[r]*0.125f : -3.0e38f;
      }
    }
    float mloc = p[0];
#pragma unroll
    for (int i=1;i<8;i++) mloc = fmaxf(mloc, p[i]);
    mloc = fmaxf(mloc, __shfl_xor(mloc, 16));
    mloc = fmaxf(mloc, __shfl_xor(mloc, 32));
    const float mnew = fmaxf(mrun, mloc);
    const float corr = __expf(mrun - mnew);
    float ls = 0.f;
#pragma unroll
    for (int i=0;i<8;i++) { p[i] = __expf(p[i] - mnew); ls += p[i]; }
    ls += __shfl_xor(ls, 16); ls += __shfl_xor(ls, 32);
    lrun = lrun * corr + ls;
    mrun = mnew;
    // P (q=l15, key_local=s*16+g*4+r) -> LDS -> PV A-frag (q=l15, key_local=g*8+j)
#pragma unroll
    for (int s=0;s<2;s++) {
      bf16x4 pw;
#pragma unroll
      for (int r=0;r<4;r++) pw[r] = (__bf16)p[s*4+r];
      *(bf16x4*)(&Plds[wv][l15*40 + s*16 + g*4]) = pw;
    }
    const bf16x8 pa = *(const bf16x8*)(&Plds[wv][l15*40 + g*8]);
    float cr[4];
#pragma unroll
    for (int r=0;r<4;r++) cr[r] = __shfl(corr, g*4 + r);
#pragma unroll
    for (int db=0; db<4; db++)
#pragma unroll
      for (int r=0;r<4;r++) o[db][r] *= cr[r];
#pragma unroll
    for (int db=0; db<4; db++) {
      bf16x8 vf;
#pragma unroll
      for (int j=0;j<8;j++)
        vf[j] = V[base + (size_t)(kt + g*8 + j)*D_ + db*16 + l15];
      o[db] = mfma16(pa, vf, o[db]);
    }
  }
  const float inv = 1.f / lrun;
  float ir[4];
#pragma unroll
  for (int r=0;r<4;r++) ir[r] = __shfl(inv, g*4 + r);
#pragma unroll
  for (int db=0; db<4; db++)
#pragma unroll
    for (int r=0;r<4;r++)
      O[base + (size_t)(q0 + g*4 + r)*D_ + db*16 + l15] = (__bf16)(o[db][r] * ir[r]);
}

// ---------------- transpose + f32->bf16: W[R,C] -> Wt[C,R] ----------------
__global__ __launch_bounds__(256) void transcvt(const float* __restrict__ W, __bf16* __restrict__ Wt,
                                                int R, int C) {
  __shared__ float tile[32][33];
  const int tx = threadIdx.x & 31, ty = threadIdx.x >> 5;
  const int r0 = blockIdx.y*32, c0 = blockIdx.x*32;
#pragma unroll
  for (int i=0;i<4;i++) tile[ty+i*8][tx] = W[(size_t)(r0+ty+i*8)*C + c0+tx];
  __syncthreads();
#pragma unroll
  for (int i=0;i<4;i++) Wt[(size_t)(c0+ty+i*8)*R + r0+tx] = (__bf16)tile[tx][ty+i*8];
}

// ---------------- fused residual + LayerNorm: zout = LN(zin+yin)*g+b; writes f32 + bf16 ----------------
__global__ __launch_bounds__(256) void ln_k(const float* __restrict__ zin, const float* __restrict__ yin,
                                            const float* __restrict__ gam, const float* __restrict__ bet,
                                            float* __restrict__ zout, __bf16* __restrict__ zbout) {
  const int row = blockIdx.x, tid = threadIdx.x;
  const f32x4 zv = ((const f32x4*)(zin + (size_t)row*D_))[tid];
  const f32x4 yv = ((const f32x4*)(yin + (size_t)row*D_))[tid];
  f32x4 v = zv + yv;
  float s1 = v[0]+v[1]+v[2]+v[3];
  float s2 = v[0]*v[0]+v[1]*v[1]+v[2]*v[2]+v[3]*v[3];
#pragma unroll
  for (int off=32; off; off>>=1) { s1 += __shfl_xor(s1,off); s2 += __shfl_xor(s2,off); }
  __shared__ float red[8];
  const int wv = tid>>6, ln = tid&63;
  if (ln==0) { red[wv] = s1; red[4+wv] = s2; }
  __syncthreads();
  s1 = red[0]+red[1]+red[2]+red[3];
  s2 = red[4]+red[5]+red[6]+red[7];
  const float mean = s1 * (1.f/1024.f);
  const float var = s2 * (1.f/1024.f) - mean*mean;
  const float rs = rsqrtf(var + 1e-5f);
  const f32x4 gv = ((const f32x4*)gam)[tid];
  const f32x4 bv = ((const f32x4*)bet)[tid];
  f32x4 r; bf16x4 rb;
#pragma unroll
  for (int j=0;j<4;j++) { float t = (v[j]-mean)*rs*gv[j] + bv[j]; r[j] = t; rb[j] = (__bf16)t; }
  ((f32x4*)(zout + (size_t)row*D_))[tid] = r;
  ((bf16x4*)(zbout + (size_t)row*D_))[tid] = rb;
}

// ---------------- cond MLP branch hiddens: h = silu(u@w1+b1), three branches ----------------
__global__ __launch_bounds__(256) void cond1_k(const int* __restrict__ t, const float* __restrict__ target,
                                               const float* __restrict__ action,
                                               const float* __restrict__ t_w1, const float* __restrict__ t_b1,
                                               const float* __restrict__ tg_w1, const float* __restrict__ tg_b1,
                                               const float* __restrict__ ac_w1, const float* __restrict__ ac_b1,
                                               float* __restrict__ h3) {
  const int i = blockIdx.x*256 + threadIdx.x;  // 8192
  const int b = i >> 10, d = i & 1023;
  float u = (float)t[b] * t_w1[d] + t_b1[d];
  h3[i] = u / (1.f + __expf(-u));
  u = tg_b1[d];
#pragma unroll
  for (int j=0;j<3;j++) u += target[b*3+j]*tg_w1[j*1024+d];
  h3[8192 + i] = u / (1.f + __expf(-u));
  u = ac_b1[d];
#pragma unroll
  for (int j=0;j<5;j++) u += action[b*5+j]*ac_w1[j*1024+d];
  h3[16384 + i] = u / (1.f + __expf(-u));
}

// cond second linear, K split into 8 partials for parallelism
__global__ __launch_bounds__(256) void cond2_k(const float* __restrict__ h3,
                                               const float* __restrict__ t_w2, const float* __restrict__ tg_w2,
                                               const float* __restrict__ ac_w2, float* __restrict__ cpart) {
  const int i = blockIdx.x*256 + threadIdx.x;
  const int ks = blockIdx.y;
  const int b = i >> 10, d = i & 1023;
  const float* ht = h3 + b*1024;
  const float* hg = h3 + 8192 + b*1024;
  const float* ha = h3 + 16384 + b*1024;
  float a = 0.f;
  for (int k = ks*128; k < ks*128+128; ++k)
    a += ht[k]*t_w2[(size_t)k*1024+d] + hg[k]*tg_w2[(size_t)k*1024+d] + ha[k]*ac_w2[(size_t)k*1024+d];
  cpart[ks*8192 + i] = a;
}

// ---------------- embedding: z = in_proj(seq) + PE + cond; writes z(f32), zb, memb(bf16) ----------------
__global__ __launch_bounds__(256) void embed_k(const float* __restrict__ x, const float* __restrict__ hist,
                                               const float* __restrict__ in_w, const float* __restrict__ in_b,
                                               const float* __restrict__ cpart,
                                               const float* __restrict__ t_b2, const float* __restrict__ tg_b2,
                                               const float* __restrict__ ac_b2,
                                               float* __restrict__ z, __bf16* __restrict__ zb,
                                               __bf16* __restrict__ memb) {
  const int row = blockIdx.x;
  const int b = row / T_, tt = row - b*T_;
  const float* feat = (tt < HIST_) ? (hist + ((size_t)b*HIST_ + tt)*10) : (x + ((size_t)b*S_ + (tt-HIST_))*10);
  float f[10];
#pragma unroll
  for (int s=0;s<10;s++) f[s] = feat[s];
  const float te = (float)((tt < HIST_) ? tt : tt - HIST_);
  const int d0 = threadIdx.x*4;
#pragma unroll
  for (int u=0;u<4;u++) {
    const int d = d0+u;
    const float freq = __expf((float)(d & ~1) * (-9.210340371976184f/1024.f));
    const float ang = te * freq;
    const float pe = (d & 1) ? cosf(ang) : sinf(ang);
    float a = in_b[d] + pe + t_b2[d] + tg_b2[d] + ac_b2[d];
    const int cd = b*1024 + d;
#pragma unroll
    for (int ks=0;ks<8;ks++) a += cpart[ks*8192 + cd];
#pragma unroll
    for (int s=0;s<10;s++) a += f[s]*in_w[s*1024+d];
    z[(size_t)row*D_ + d] = a;
    const __bf16 ab = (__bf16)a;
    zb[(size_t)row*D_ + d] = ab;
    memb[(size_t)row*D_ + d] = ab;
  }
}

// ---------------- output projection: out[b,s,:] = z[b,128+s,:] @ out_w + out_b ----------------
__global__ __launch_bounds__(256) void outp_k(const float* __restrict__ z, const float* __restrict__ w,
                                              const float* __restrict__ bo, float* __restrict__ out) {
  const int wv = threadIdx.x>>6, ln = threadIdx.x&63;
  const int row = blockIdx.x*4 + wv;     // 0..8191
  const int b = row >> 10, s = row & 1023;
  const float* zr = z + ((size_t)b*T_ + HIST_ + s)*D_;
  float acc[10];
#pragma unroll
  for (int o=0;o<10;o++) acc[o]=0.f;
  for (int k=ln; k<1024; k+=64) {
    const float zv = zr[k];
    const float* wr = w + k*10;
#pragma unroll
    for (int o=0;o<10;o++) acc[o] += zv*wr[o];
  }
#pragma unroll
  for (int o=0;o<10;o++) {
#pragma unroll
    for (int off=32; off; off>>=1) acc[o] += __shfl_xor(acc[o], off);
  }
  if (ln==0) {
#pragma unroll
    for (int o=0;o<10;o++) out[(size_t)row*10+o] = acc[o] + bo[o];
  }
}

extern "C" void kernel_launch(void* const* d_in, const int* in_sizes, int n_in,
                              void* d_out, int out_size, void* d_ws, size_t ws_size,
                              hipStream_t stream) {
  const float* x      = (const float*)d_in[0];
  const int*   t      = (const int*)  d_in[1];
  const float* target = (const float*)d_in[2];
  const float* action = (const float*)d_in[3];
  const float* hist   = (const float*)d_in[4];
  const float* in_w   = (const float*)d_in[5];
  const float* in_b   = (const float*)d_in[6];
  const float* t_w1   = (const float*)d_in[7];
  const float* t_b1   = (const float*)d_in[8];
  const float* t_w2   = (const float*)d_in[9];
  const float* t_b2   = (const float*)d_in[10];
  const float* tg_w1  = (const float*)d_in[11];
  const float* tg_b1  = (const float*)d_in[12];
  const float* tg_w2  = (const float*)d_in[13];
  const float* tg_b2  = (const float*)d_in[14];
  const float* ac_w1  = (const float*)d_in[15];
  const float* ac_b1  = (const float*)d_in[16];
  const float* ac_w2  = (const float*)d_in[17];
  const float* ac_b2  = (const float*)d_in[18];
  const float* sa_wq  = (const float*)d_in[19];
  const float* sa_bq  = (const float*)d_in[20];
  const float* sa_wk  = (const float*)d_in[21];
  const float* sa_bk  = (const float*)d_in[22];
  const float* sa_wv  = (const float*)d_in[23];
  const float* sa_bv  = (const float*)d_in[24];
  const float* sa_wo  = (const float*)d_in[25];
  const float* sa_bo  = (const float*)d_in[26];
  const float* ca_wq  = (const float*)d_in[27];
  const float* ca_bq  = (const float*)d_in[28];
  const float* ca_wk  = (const float*)d_in[29];
  const float* ca_bk  = (const float*)d_in[30];
  const float* ca_wv  = (const float*)d_in[31];
  const float* ca_bv  = (const float*)d_in[32];
  const float* ca_wo  = (const float*)d_in[33];
  const float* ca_bo  = (const float*)d_in[34];
  const float* ln1_g  = (const float*)d_in[35];
  const float* ln1_b  = (const float*)d_in[36];
  const float* ln2_g  = (const float*)d_in[37];
  const float* ln2_b  = (const float*)d_in[38];
  const float* ln3_g  = (const float*)d_in[39];
  const float* ln3_b  = (const float*)d_in[40];
  const float* ff_w1  = (const float*)d_in[41];
  const float* ff_b1  = (const float*)d_in[42];
  const float* ff_w2  = (const float*)d_in[43];
  const float* ff_b2  = (const float*)d_in[44];
  const float* out_w  = (const float*)d_in[45];
  const float* out_b  = (const float*)d_in[46];

  if (ws_size < (size_t)225*1024*1024) return;  // workspace plan needs ~213 MiB

  char* p = (char*)d_ws;
  auto take = [&](size_t bytes) { char* r = p; p += (bytes + 255) & ~(size_t)255; return r; };
  __bf16* wbuf = (__bf16*)take((size_t)16*1024*1024*2);   // per-layer transposed bf16 weights
  float*  z    = (float*) take((size_t)NROWS_*D_*4);
  __bf16* zb   = (__bf16*)take((size_t)NROWS_*D_*2);
  __bf16* memb = (__bf16*)take((size_t)NROWS_*D_*2);
  __bf16* qb   = (__bf16*)take((size_t)NROWS_*D_*2);
  __bf16* kb   = (__bf16*)take((size_t)NROWS_*D_*2);
  __bf16* vb   = (__bf16*)take((size_t)NROWS_*D_*2);
  __bf16* ob   = (__bf16*)take((size_t)NROWS_*D_*2);
  float*  y    = (float*) take((size_t)NROWS_*D_*4);
  float*  h3   = (float*) take((size_t)3*8192*4);
  float*  cpart= (float*) take((size_t)8*8192*4);
  __bf16* ffh  = qb;   // FFN hidden [9216,4096] aliases qb..ob (exact size match)

  const dim3 blk(256);
  cond1_k<<<32, blk, 0, stream>>>(t, target, action, t_w1, t_b1, tg_w1, tg_b1, ac_w1, ac_b1, h3);
  cond2_k<<<dim3(32,8), blk, 0, stream>>>(h3, t_w2, tg_w2, ac_w2, cpart);
  embed_k<<<NROWS_, blk, 0, stream>>>(x, hist, in_w, in_b, cpart, t_b2, tg_b2, ac_b2, z, zb, memb);

  const int M = NROWS_;
  for (int li=0; li<L_; ++li) {
    const size_t w0 = (size_t)li*D_*D_, b0 = (size_t)li*D_;
    const size_t f1 = (size_t)li*D_*FF_, fb1 = (size_t)li*FF_;
    transcvt<<<dim3(32,32), blk, 0, stream>>>(sa_wq + w0, wbuf + 0*1048576, 1024, 1024);
    transcvt<<<dim3(32,32), blk, 0, stream>>>(sa_wk + w0, wbuf + 1*1048576, 1024, 1024);
    transcvt<<<dim3(32,32), blk, 0, stream>>>(sa_wv + w0, wbuf + 2*1048576, 1024, 1024);
    transcvt<<<dim3(32,32), blk, 0, stream>>>(sa_wo + w0, wbuf + 3*1048576, 1024, 1024);
    transcvt<<<dim3(32,32), blk, 0, stream>>>(ca_wq + w0, wbuf + 4*1048576, 1024, 1024);
    transcvt<<<dim3(32,32), blk, 0, stream>>>(ca_wk + w0, wbuf + 5*1048576, 1024, 1024);
    transcvt<<<dim3(32,32), blk, 0, stream>>>(ca_wv + w0, wbuf + 6*1048576, 1024, 1024);
    transcvt<<<dim3(32,32), blk, 0, stream>>>(ca_wo + w0, wbuf + 7*1048576, 1024, 1024);
    transcvt<<<dim3(128,32), blk, 0, stream>>>(ff_w1 + f1, wbuf + (size_t)8*1048576, 1024, 4096);
    transcvt<<<dim3(32,128), blk, 0, stream>>>(ff_w2 + f1, wbuf + (size_t)12*1048576, 4096, 1024);
    // self-attention
    gemm_k<1,0><<<dim3(8,72), blk, 0, stream>>>(zb, wbuf+0*1048576, sa_bq+b0, qb, M, 1024, 1024);
    gemm_k<1,0><<<dim3(8,72), blk, 0, stream>>>(zb, wbuf+1*1048576, sa_bk+b0, kb, M, 1024, 1024);
    gemm_k<1,0><<<dim3(8,72), blk, 0, stream>>>(zb, wbuf+2*1048576, sa_bv+b0, vb, M, 1024, 1024);
    attn_k<<<dim3(18,16,8), blk, 0, stream>>>(qb, kb, vb, ob);
    gemm_k<0,0><<<dim3(8,72), blk, 0, stream>>>(ob, wbuf+3*1048576, sa_bo+b0, y, M, 1024, 1024);
    ln_k<<<NROWS_, blk, 0, stream>>>(z, y, ln1_g+b0, ln1_b+b0, z, zb);
    // cross-attention (memory = embedded input sequence)
    gemm_k<1,0><<<dim3(8,72), blk, 0, stream>>>(zb,   wbuf+4*1048576, ca_bq+b0, qb, M, 1024, 1024);
    gemm_k<1,0><<<dim3(8,72), blk, 0, stream>>>(memb, wbuf+5*1048576, ca_bk+b0, kb, M, 1024, 1024);
    gemm_k<1,0><<<dim3(8,72), blk, 0, stream>>>(memb, wbuf+6*1048576, ca_bv+b0, vb, M, 1024, 1024);
    attn_k<<<dim3(18,16,8), blk, 0, stream>>>(qb, kb, vb, ob);
    gemm_k<0,0><<<dim3(8,72), blk, 0, stream>>>(ob, wbuf+7*1048576, ca_bo+b0, y, M, 1024, 1024);
    ln_k<<<NROWS_, blk, 0, stream>>>(z, y, ln2_g+b0, ln2_b+b0, z, zb);
    // FFN
    gemm_k<1,1><<<dim3(32,72), blk, 0, stream>>>(zb, wbuf+(size_t)8*1048576, ff_b1+fb1, ffh, M, 4096, 1024);
    gemm_k<0,0><<<dim3(8,72), blk, 0, stream>>>(ffh, wbuf+(size_t)12*1048576, ff_b2+b0, y, M, 1024, 4096);
    ln_k<<<NROWS_, blk, 0, stream>>>(z, y, ln3_g+b0, ln3_b+b0, z, zb);
  }
  outp_k<<<2048, blk, 0, stream>>>(z, out_w, out_b, (float*)d_out);
}